// Round 10
// baseline (151.719 us; speedup 1.0000x reference)
//
#include <hip/hip_runtime.h>
#include <hip/hip_bf16.h>
#include <cstdint>

typedef __bf16 bf16x8 __attribute__((ext_vector_type(8)));
typedef __bf16 bf16x4 __attribute__((ext_vector_type(4)));
typedef float  f32x4  __attribute__((ext_vector_type(4)));
typedef float  f32x4u __attribute__((ext_vector_type(4), aligned(4)));   // 4B-aligned vec load/store
typedef __bf16 bf16x4u __attribute__((ext_vector_type(4), aligned(2)));
typedef unsigned short u16x4 __attribute__((ext_vector_type(4), aligned(2)));

__device__ __forceinline__ int div25(int v) { return (v * 1311) >> 15; }  // exact for v <= 1310

#if __has_builtin(__builtin_amdgcn_exp2f)
__device__ __forceinline__ float fast_exp2(float x) { return __builtin_amdgcn_exp2f(x); }
#else
__device__ __forceinline__ float fast_exp2(float x) { return exp2f(x); }
#endif

// async global->LDS, 16B per lane; dest must be wave-uniform base + lane*16 (linear)
__device__ __forceinline__ void gll16(const __bf16* g, __bf16* l)
{
    __builtin_amdgcn_global_load_lds(
        (__attribute__((address_space(1))) void*)(g),
        (__attribute__((address_space(3))) void*)(l),
        16, 0, 0);
}

// ---- inline dtype sniff: 16 uniform halfwords from one cache line ----
__device__ __forceinline__ int sniff_isbf(const void* p)
{
    const unsigned short* x = (const unsigned short*)p;
    int cnt = 0;
    #pragma unroll
    for (int i = 0; i < 16; ++i) {
        int e = (x[2 * i] >> 7) & 0xFF;
        cnt += (e >= 90 && e <= 143) ? 1 : 0;
    }
    return cnt > 8;
}

// ================= fused preprocessing: one launch, 3 independent jobs =================
// blocks [0,1280): x transpose+cvt, VECTORIZED (f32x4 loads, bf16x4 stores)
// blocks [1280,1344): weight prep (own 65-stride view of the shared pool)
// blocks [1344,1384): bias table, h-FUSED: one block per ig computes ALL 8 heads
//   (idx math /8, rel[idx*8..+7] read as ONE vector instead of 8 scalar reads)
__global__ __launch_bounds__(256) void k_pre(
    const void* __restrict__ x, const void* __restrict__ Wqkv,
    const void* __restrict__ Wout, const void* __restrict__ rel,
    __bf16* __restrict__ xT, __bf16* __restrict__ Wt, __bf16* __restrict__ WoT,
    __bf16* __restrict__ biasC)
{
    __shared__ __align__(16) float shpool[64 * 68];   // 17.4 KB, shared by both tile users
    int bid = blockIdx.x;
    if (bid < 1280) {
        // ---- x transpose, vectorized ----
        float (*tile)[68] = (float(*)[68])shpool;     // stride 68: 16B-aligned rows
        int isbf = sniff_isbf(x);
        int b = bid / 40, rem = bid % 40;
        int c0 = (rem % 10) * 64, r0 = (rem / 10) * 64;
        const int R = 256, C = 625;
        int t = threadIdx.x;
        int lr4 = (t >> 4) * 4;    // 0..60
        int lc4 = (t & 15) * 4;    // 0..60
        const unsigned short* sb = (const unsigned short*)x + (size_t)b * (256 * 625);
        const float*          sf = (const float*)x          + (size_t)b * (256 * 625);
        #pragma unroll
        for (int rr = 0; rr < 4; ++rr) {
            int r = r0 + lr4 + rr;
            int c = c0 + lc4;
            f32x4 v = {0.f, 0.f, 0.f, 0.f};
            if (c + 3 < C) {
                if (isbf) {
                    u16x4 u = *(const u16x4*)(sb + (size_t)r * C + c);
                    #pragma unroll
                    for (int j = 0; j < 4; ++j) v[j] = __uint_as_float((unsigned)u[j] << 16);
                } else {
                    v = *(const f32x4u*)(sf + (size_t)r * C + c);
                }
            } else {
                #pragma unroll
                for (int j = 0; j < 4; ++j) {
                    int cc2 = c + j;
                    if (cc2 < C) {
                        if (isbf) v[j] = __uint_as_float((unsigned)sb[(size_t)r * C + cc2] << 16);
                        else      v[j] = sf[(size_t)r * C + cc2];
                    }
                }
            }
            *(f32x4*)(&tile[lr4 + rr][lc4]) = v;
        }
        __syncthreads();
        __bf16* d = xT + (size_t)b * (640 * 256);
        int lc = t & 63, rc = (t >> 6) * 16;
        int c = c0 + lc;
        #pragma unroll
        for (int k = 0; k < 4; ++k) {
            bf16x4 o4;
            #pragma unroll
            for (int j = 0; j < 4; ++j) o4[j] = (__bf16)tile[rc + k * 4 + j][lc];
            *(bf16x4*)(d + (size_t)c * R + r0 + rc + k * 4) = o4;
        }
    } else if (bid < 1344) {
        // ---- weight prep ----
        float (*tile)[65] = (float(*)[65])shpool;
        int q = bid - 1280;
        int bx = q % 16, by = q / 16;
        int isbf = sniff_isbf(Wqkv);
        int isqkv = (bx < 12);
        int bxx = isqkv ? bx : (bx - 12);
        const void* src = isqkv ? Wqkv : Wout;
        __bf16* dst = isqkv ? Wt : WoT;
        int R = 256, C = isqkv ? 768 : 256;
        int r0 = by * 64, c0 = bxx * 64;
        int tc = threadIdx.x & 63, tg = threadIdx.x >> 6;
        const unsigned short* sb = (const unsigned short*)src;
        const float*          sf = (const float*)src;
        #pragma unroll
        for (int rr = 0; rr < 16; ++rr) {
            int r = r0 + tg * 16 + rr, c = c0 + tc;
            float v;
            if (isbf) v = __uint_as_float((unsigned int)sb[r * C + c] << 16);
            else      v = sf[r * C + c];
            tile[tg * 16 + rr][tc] = v;
        }
        __syncthreads();
        const float qs = 0.25503494f;  // 32^-0.5 * log2(e)
        #pragma unroll
        for (int rr = 0; rr < 16; ++rr) {
            int c = c0 + tg * 16 + rr, r = r0 + tc;
            float v = tile[tc][tg * 16 + rr];
            if (isqkv && c < 256) v *= qs;
            dst[(size_t)c * R + r] = (__bf16)v;
        }
    } else {
        // ---- bias table, all 8 heads per block (packed per-lane layout, bf16) ----
        const float LOG2E = 1.4426950408889634f;
        int isbf = sniff_isbf(rel);
        int ig = bid - 1344;              // 0..39
        const __bf16* relb = (const __bf16*)rel;
        const float*  relf = (const float*)rel;
        for (int t0 = 0; t0 < 10; ++t0) {
            int t  = t0 * 256 + threadIdx.x;
            int jc = t >> 7;
            int js = (t >> 6) & 1;
            int ln = t & 63;
            int qd = ln >> 4, l = ln & 15;
            int i = ig * 16 + l;
            int di = div25(i), ri = i - 25 * di;
            bf16x4 outh[8];
            #pragma unroll
            for (int rr = 0; rr < 4; ++rr) {
                int j = jc * 32 + js * 16 + qd * 4 + rr;
                if (j >= 625) {
                    #pragma unroll
                    for (int h = 0; h < 8; ++h) outh[h][rr] = (__bf16)(-43281.f);
                } else {
                    int dj = div25(j);
                    int idx = (di - dj + 24) * 49 + ri - (j - 25 * dj) + 24;
                    idx = min(max(idx, 0), 2400);
                    if (isbf) {
                        bf16x8 r8 = *(const bf16x8*)(relb + (size_t)idx * 8);
                        #pragma unroll
                        for (int h = 0; h < 8; ++h) outh[h][rr] = (__bf16)((float)r8[h] * LOG2E);
                    } else {
                        f32x4u ra = *(const f32x4u*)(relf + (size_t)idx * 8);
                        f32x4u rb = *(const f32x4u*)(relf + (size_t)idx * 8 + 4);
                        #pragma unroll
                        for (int h = 0; h < 4; ++h) outh[h][rr]     = (__bf16)(ra[h] * LOG2E);
                        #pragma unroll
                        for (int h = 0; h < 4; ++h) outh[4 + h][rr] = (__bf16)(rb[h] * LOG2E);
                    }
                }
            }
            #pragma unroll
            for (int h = 0; h < 8; ++h)
                *(bf16x4*)(biasC + ((size_t)(h * 40 + ig) * 20 + jc) * 512 + ln * 8 + js * 4) = outh[h];
        }
    }
}

// -------- QKV projection, 128x128 tile, BK=32, 2-phase double-buffered gll16 ----------
// (byte-identical to R7/R8/R9)
#define AS(bf, r, c) pool[(size_t)(bf) * 8192 + (size_t)(r) * 32 + (c)]
#define BS(bf, r, c) pool[(size_t)(bf) * 8192 + 4096 + (size_t)(r) * 32 + (c)]
#define CS(r, c)     pool[(size_t)(r) * 44 + (c)]
__global__ __launch_bounds__(256, 2) void k_qkv(
    const __bf16* __restrict__ xT,   // (b,640,256), pad rows zeroed
    const __bf16* __restrict__ Wt,   // (768,256)
    __bf16* __restrict__ Q,          // (b,8,640,32) scaled by 32^-.5*log2e
    __bf16* __restrict__ Km,         // (b,8,640,32)
    __bf16* __restrict__ Vt)         // (b,8,32,640)
{
    __shared__ __align__(16) __bf16 pool[16384];
    int L = blockIdx.x;
    int xcd = L & 7;
    int cc  = L >> 3;
    int pairIdx = xcd * 20 + cc / 6;
    int jt = cc - (cc / 6) * 6;
    int b  = pairIdx / 5;
    int pt = pairIdx - b * 5;
    int p0 = pt * 128, j0 = jt * 128;
    int tid = threadIdx.x;
    int w = tid >> 6, lane = tid & 63;
    int quad = lane >> 4, l15 = lane & 15;
    int wr = w >> 1, wc = w & 1;

    int srow = tid >> 2, scg = (tid & 3) * 8;
    const __bf16* ag  = xT + ((size_t)(b * 640 + p0 + srow) * 256) + scg;
    const __bf16* ag2 = ag + 64 * 256;
    const __bf16* bg  = Wt + ((size_t)(j0 + srow) * 256) + scg;
    const __bf16* bg2 = bg + 64 * 256;

    gll16(ag,  &AS(0, srow, scg));
    gll16(ag2, &AS(0, 64 + srow, scg));
    gll16(bg,  &BS(0, srow, scg));
    gll16(bg2, &BS(0, 64 + srow, scg));
    __syncthreads();

    f32x4 acc[4][4] = {};
    for (int kk = 0; kk < 8; ++kk) {
        int cur = kk & 1;
        if (kk < 7) {
            int c0 = (kk + 1) * 32;
            int nb = cur ^ 1;
            gll16(ag  + c0, &AS(nb, srow, scg));
            gll16(ag2 + c0, &AS(nb, 64 + srow, scg));
            gll16(bg  + c0, &BS(nb, srow, scg));
            gll16(bg2 + c0, &BS(nb, 64 + srow, scg));
        }
        bf16x8 af[4], bfr[4];
        #pragma unroll
        for (int t = 0; t < 4; ++t) {
            af[t]  = *(const bf16x8*)(&AS(cur, wr * 64 + t * 16 + l15, quad * 8));
            bfr[t] = *(const bf16x8*)(&BS(cur, wc * 64 + t * 16 + l15, quad * 8));
        }
        #pragma unroll
        for (int i = 0; i < 4; ++i)
            #pragma unroll
            for (int j = 0; j < 4; ++j)
                acc[i][j] = __builtin_amdgcn_mfma_f32_16x16x32_bf16(af[i], bfr[j], acc[i][j], 0, 0, 0);
        __syncthreads();
    }

    if (jt < 4) {
        for (int r = 0; r < 4; ++r) {
            __syncthreads();
            if (wc == (r >> 1)) {
                #pragma unroll
                for (int i = 0; i < 4; ++i) {
                    #pragma unroll
                    for (int js = 0; js < 2; ++js) {
                        int jp = (r & 1) * 2 + js;
                        int col = js * 16 + l15;
                        int prow = wr * 64 + i * 16 + quad * 4;
                        #pragma unroll
                        for (int rr = 0; rr < 4; ++rr)
                            CS(prow + rr, col) = (__bf16)acc[i][jp][rr];
                    }
                }
            }
            __syncthreads();
            int jj = j0 + r * 32;
            __bf16* dst; int hh;
            if (jj < 256) { hh = jj >> 5; dst = Q; }
            else          { hh = (jj - 256) >> 5; dst = Km; }
            int p = tid >> 1, d0 = (tid & 1) * 16;
            size_t base = ((size_t)((b * 8 + hh) * 640) + p0 + p) * 32 + d0;
            #pragma unroll
            for (int k4 = 0; k4 < 4; ++k4) {
                bf16x4 v4 = *(const bf16x4*)(&CS(p, d0 + k4 * 4));
                *(bf16x4*)(dst + base + k4 * 4) = v4;
            }
        }
    } else {
        #pragma unroll
        for (int i = 0; i < 4; ++i) {
            #pragma unroll
            for (int j = 0; j < 4; ++j) {
                int jj = j0 + wc * 64 + j * 16 + l15 - 512;
                int h = jj >> 5, t = jj & 31;
                int p = p0 + wr * 64 + i * 16 + quad * 4;
                bf16x4 vv;
                #pragma unroll
                for (int rr = 0; rr < 4; ++rr) vv[rr] = (__bf16)acc[i][j][rr];
                *(bf16x4*)(Vt + ((size_t)((b * 8 + h) * 32) + t) * 640 + p) = vv;
            }
        }
    }
}

// -------- fused attention v14: one 640-thread block per bh (byte-identical to R9) -----
__global__ __launch_bounds__(640, 2) void k_attn(
    const __bf16* __restrict__ Q,
    const __bf16* __restrict__ Km,
    const __bf16* __restrict__ Vt,
    const __bf16* __restrict__ biasC,  // packed C-fragment order, *log2e
    __bf16* __restrict__ ctx)          // (b,640,256), channel = h*32+dh
{
    __shared__ __align__(16) __bf16 P[10][2][64][44];  // [wave][buf][i][j] 112.5 KB
    __shared__ float ssum[10][64];
    int bh = blockIdx.x, b = bh >> 3, h = bh & 7;
    int tid = threadIdx.x, w = tid >> 6, lane = tid & 63;
    int quad = lane >> 4, l15 = lane & 15;
    int i0 = w * 64;

    bf16x8 qa[4];
    #pragma unroll
    for (int m = 0; m < 4; ++m)
        qa[m] = *(const bf16x8*)(Q + ((size_t)bh * 640 + i0 + 16 * m + l15) * 32 + quad * 8);
    const __bf16* kbase = Km + (size_t)bh * 640 * 32 + quad * 8;
    const __bf16* vbase = Vt + ((size_t)bh * 32 + l15) * 640 + quad * 8;
    const __bf16* bcb   = biasC + (size_t)(h * 40 + (i0 >> 4)) * 10240 + lane * 8;

    f32x4 o[4][2] = {};
    float psum[4] = {0.f, 0.f, 0.f, 0.f};

    bf16x8 k0 = *(const bf16x8*)(kbase + (size_t)l15 * 32);
    bf16x8 k1 = *(const bf16x8*)(kbase + (size_t)(16 + l15) * 32);
    bf16x8 bc[4];
    #pragma unroll
    for (int m = 0; m < 4; ++m)
        bc[m] = *(const bf16x8*)(bcb + m * 10240);
    bf16x8 vC0 = {}, vC1 = {};

    for (int c = 0; c < 20; ++c) {
        int buf = c & 1;
        f32x4 s[4][2];
        __builtin_amdgcn_s_setprio(1);
        #pragma unroll
        for (int m = 0; m < 4; ++m) {
            f32x4 f0, f1;
            #pragma unroll
            for (int rr = 0; rr < 4; ++rr) { f0[rr] = (float)bc[m][rr]; f1[rr] = (float)bc[m][4 + rr]; }
            s[m][0] = __builtin_amdgcn_mfma_f32_16x16x32_bf16(k0, qa[m], f0, 0, 0, 0);
            s[m][1] = __builtin_amdgcn_mfma_f32_16x16x32_bf16(k1, qa[m], f1, 0, 0, 0);
        }
        __builtin_amdgcn_s_setprio(0);
        int cn = min(c + 1, 19);
        bf16x8 k0n = *(const bf16x8*)(kbase + (size_t)(cn * 32 + l15) * 32);
        bf16x8 k1n = *(const bf16x8*)(kbase + (size_t)(cn * 32 + 16 + l15) * 32);
        bf16x8 vN0 = *(const bf16x8*)(vbase + c * 32);
        bf16x8 vN1 = *(const bf16x8*)(vbase + (size_t)16 * 640 + c * 32);
        bf16x8 bn[4];
        #pragma unroll
        for (int m = 0; m < 4; ++m)
            bn[m] = *(const bf16x8*)(bcb + m * 10240 + cn * 512);
        bf16x4 pk[4][2];
        #pragma unroll
        for (int m = 0; m < 4; ++m) {
            #pragma unroll
            for (int rr = 0; rr < 4; ++rr) {
                float e0 = fast_exp2(s[m][0][rr]); psum[m] += e0; pk[m][0][rr] = (__bf16)e0;
                float e1 = fast_exp2(s[m][1][rr]); psum[m] += e1; pk[m][1][rr] = (__bf16)e1;
            }
        }
        if (c > 0) {
            __builtin_amdgcn_s_setprio(1);
            #pragma unroll
            for (int m = 0; m < 4; ++m) {
                bf16x8 pa = *(const bf16x8*)(&P[w][buf ^ 1][16 * m + l15][quad * 8]);
                o[m][0] = __builtin_amdgcn_mfma_f32_16x16x32_bf16(pa, vC0, o[m][0], 0, 0, 0);
                o[m][1] = __builtin_amdgcn_mfma_f32_16x16x32_bf16(pa, vC1, o[m][1], 0, 0, 0);
            }
            __builtin_amdgcn_s_setprio(0);
        }
        #pragma unroll
        for (int m = 0; m < 4; ++m) {
            *(bf16x4*)(&P[w][buf][16 * m + l15][quad * 4])      = pk[m][0];
            *(bf16x4*)(&P[w][buf][16 * m + l15][16 + quad * 4]) = pk[m][1];
        }
        k0 = k0n; k1 = k1n; vC0 = vN0; vC1 = vN1;
        #pragma unroll
        for (int m = 0; m < 4; ++m) bc[m] = bn[m];
    }
    __builtin_amdgcn_s_setprio(1);
    #pragma unroll
    for (int m = 0; m < 4; ++m) {
        bf16x8 pa = *(const bf16x8*)(&P[w][1][16 * m + l15][quad * 8]);
        o[m][0] = __builtin_amdgcn_mfma_f32_16x16x32_bf16(pa, vC0, o[m][0], 0, 0, 0);
        o[m][1] = __builtin_amdgcn_mfma_f32_16x16x32_bf16(pa, vC1, o[m][1], 0, 0, 0);
    }
    __builtin_amdgcn_s_setprio(0);

    #pragma unroll
    for (int m = 0; m < 4; ++m) {
        psum[m] += __shfl_xor(psum[m], 16);
        psum[m] += __shfl_xor(psum[m], 32);
    }
    if (quad == 0)
        #pragma unroll
        for (int m = 0; m < 4; ++m) ssum[w][16 * m + l15] = psum[m];
    #pragma unroll
    for (int m = 0; m < 4; ++m) {
        #pragma unroll
        for (int rr = 0; rr < 4; ++rr) {
            int il = 16 * m + quad * 4 + rr;
            float inv = 1.f / ssum[w][il];
            size_t base = ((size_t)b * 640 + i0 + il) * 256 + h * 32;
            ctx[base + l15]      = (__bf16)(o[m][0][rr] * inv);
            ctx[base + 16 + l15] = (__bf16)(o[m][1][rr] * inv);
        }
    }
}

// -------- output projection, 2-phase gll16 + LDS-transposed COALESCED epilogue --------
// Stores were 64-distinct-lines per instruction (co-major lanes, 2500B stride); now each
// wave transposes its 64co x 64p quarter through its private pool2 slice (stride-68 f32,
// b32-phase banks <=2-way = free) and stores 256B-contiguous runs. No new barriers:
// final main-loop __syncthreads() fences all staging reads; DS is per-wave in-order.
__global__ __launch_bounds__(256, 2) void k_outproj(
    const __bf16* __restrict__ ctx,   // (b,640,256)
    const __bf16* __restrict__ WoT,   // (256,256)
    const void* __restrict__ xorig,   // dtype sniff only
    void* __restrict__ out)           // (b,256,625)
{
    __shared__ __align__(16) __bf16 pool2[20480];
    int isbf = sniff_isbf(xorig);
    int b = blockIdx.y, pt = blockIdx.x;
    int p0 = pt * 64;
    int tid = threadIdx.x, w = tid >> 6, lane = tid & 63;
    int quad = lane >> 4, l15 = lane & 15;
    int srow = tid >> 2, scg = (tid & 3) * 8;
    const __bf16* ag = ctx + ((size_t)(b * 640 + p0 + srow) * 256) + scg;
    const __bf16* bg = WoT + (size_t)srow * 256 + scg;

    gll16(ag,            &pool2[(size_t)srow * 32 + scg]);
    gll16(bg,            &pool2[2048 + (size_t)srow * 32 + scg]);
    gll16(bg + 64 * 256, &pool2[2048 + (size_t)(64 + srow) * 32 + scg]);
    gll16(bg + 128 * 256,&pool2[2048 + (size_t)(128 + srow) * 32 + scg]);
    gll16(bg + 192 * 256,&pool2[2048 + (size_t)(192 + srow) * 32 + scg]);
    __syncthreads();

    f32x4 acc[4][4] = {};
    for (int kk = 0; kk < 8; ++kk) {
        int cur = kk & 1;
        size_t base = (size_t)cur * 10240;
        if (kk < 7) {
            int c0 = (kk + 1) * 32;
            size_t nb = (size_t)(cur ^ 1) * 10240;
            gll16(ag + c0,             &pool2[nb + (size_t)srow * 32 + scg]);
            gll16(bg + c0,             &pool2[nb + 2048 + (size_t)srow * 32 + scg]);
            gll16(bg + 64 * 256 + c0,  &pool2[nb + 2048 + (size_t)(64 + srow) * 32 + scg]);
            gll16(bg + 128 * 256 + c0, &pool2[nb + 2048 + (size_t)(128 + srow) * 32 + scg]);
            gll16(bg + 192 * 256 + c0, &pool2[nb + 2048 + (size_t)(192 + srow) * 32 + scg]);
        }
        bf16x8 af[4], bfr[4];
        #pragma unroll
        for (int t = 0; t < 4; ++t) {
            af[t]  = *(const bf16x8*)(&pool2[base + (size_t)(t * 16 + l15) * 32 + quad * 8]);
            bfr[t] = *(const bf16x8*)(&pool2[base + 2048 + (size_t)(w * 64 + t * 16 + l15) * 32 + quad * 8]);
        }
        #pragma unroll
        for (int i = 0; i < 4; ++i)
            #pragma unroll
            for (int j = 0; j < 4; ++j)
                acc[i][j] = __builtin_amdgcn_mfma_f32_16x16x32_bf16(af[i], bfr[j], acc[i][j], 0, 0, 0);
        __syncthreads();
    }

    // ---- epilogue: per-wave LDS transpose -> coalesced stores ----
    float* fpool = (float*)pool2;          // 40KB; 4 waves x 32x68 f32 = 34.8KB
    int wb = w * (32 * 68);
    __bf16* outb = (__bf16*)out;
    float*  outf = (float*)out;
    #pragma unroll
    for (int pr = 0; pr < 2; ++pr) {       // j-pairs (0,1) then (2,3)
        #pragma unroll
        for (int jp = 0; jp < 2; ++jp) {
            int j = pr * 2 + jp;
            int co_l = jp * 16 + l15;
            #pragma unroll
            for (int i = 0; i < 4; ++i)
                *(f32x4*)(&fpool[wb + co_l * 68 + i * 16 + quad * 4]) = acc[i][j];
        }
        #pragma unroll
        for (int it = 0; it < 8; ++it) {
            int co_l = it * 4 + quad;
            int co = w * 64 + pr * 32 + co_l;
            int pl = l15 * 4;
            f32x4 v = *(const f32x4*)(&fpool[wb + co_l * 68 + pl]);
            int p = p0 + pl;
            size_t o = ((size_t)(b * 256) + co) * 625 + p;
            if (p + 3 < 625) {
                if (isbf) {
                    bf16x4 v4;
                    #pragma unroll
                    for (int rr = 0; rr < 4; ++rr) v4[rr] = (__bf16)v[rr];
                    *(bf16x4u*)(outb + o) = v4;
                } else {
                    *(f32x4u*)(outf + o) = v;
                }
            } else {
                #pragma unroll
                for (int rr = 0; rr < 4; ++rr) {
                    if (p + rr < 625) {
                        if (isbf) outb[o + rr] = (__bf16)v[rr];
                        else      outf[o + rr] = v[rr];
                    }
                }
            }
        }
        // pr=1 writes reuse this wave's slice after pr=0 reads: per-wave DS is in-order.
    }
}

extern "C" void kernel_launch(void* const* d_in, const int* in_sizes, int n_in,
                              void* d_out, int out_size, void* d_ws, size_t ws_size,
                              hipStream_t stream)
{
    const void* x    = d_in[0];
    const void* Wqkv = d_in[1];
    const void* Wout = d_in[2];
    const void* rel  = d_in[3];

    // ws layout, NO aliasing (ws_size is 256 MiB per the harness fill; we use ~70 MB).
    __bf16* ws    = (__bf16*)d_ws;
    __bf16* xT    = ws;                      // 10,485,760 elems
    __bf16* Wt    = xT + 10485760;           //    196,608
    __bf16* WoT   = Wt + 196608;             //     65,536
    __bf16* Q     = WoT + 65536;             //  5,242,880
    __bf16* Km    = Q + 5242880;             //  5,242,880
    __bf16* Vt    = Km + 5242880;            //  5,242,880
    __bf16* biasC = Vt + 5242880;            //  3,276,800
    __bf16* ctx   = biasC + 3276800;         //  5,242,880   (total ~70 MB)

    k_pre<<<1384, 256, 0, stream>>>(x, Wqkv, Wout, rel, xT, Wt, WoT, biasC);
    k_qkv<<<dim3(960), 256, 0, stream>>>(xT, Wt, Q, Km, Vt);
    k_attn<<<dim3(256), 640, 0, stream>>>(Q, Km, Vt, biasC, ctx);
    k_outproj<<<dim3(10, 32), 256, 0, stream>>>(ctx, WoT, x, d_out);
}

// Round 11
// 146.920 us; speedup vs baseline: 1.0327x; 1.0327x over previous
//
#include <hip/hip_runtime.h>
#include <hip/hip_bf16.h>
#include <cstdint>

typedef __bf16 bf16x8 __attribute__((ext_vector_type(8)));
typedef __bf16 bf16x4 __attribute__((ext_vector_type(4)));
typedef float  f32x4  __attribute__((ext_vector_type(4)));
typedef float  f32x4u __attribute__((ext_vector_type(4), aligned(4)));   // 4B-aligned vec load/store
typedef __bf16 bf16x4u __attribute__((ext_vector_type(4), aligned(2)));
typedef unsigned short u16x4 __attribute__((ext_vector_type(4), aligned(2)));

__device__ __forceinline__ int div25(int v) { return (v * 1311) >> 15; }  // exact for v <= 1310

#if __has_builtin(__builtin_amdgcn_exp2f)
__device__ __forceinline__ float fast_exp2(float x) { return __builtin_amdgcn_exp2f(x); }
#else
__device__ __forceinline__ float fast_exp2(float x) { return exp2f(x); }
#endif

// async global->LDS, 16B per lane; dest must be wave-uniform base + lane*16 (linear)
__device__ __forceinline__ void gll16(const __bf16* g, __bf16* l)
{
    __builtin_amdgcn_global_load_lds(
        (__attribute__((address_space(1))) void*)(g),
        (__attribute__((address_space(3))) void*)(l),
        16, 0, 0);
}

// ---- inline dtype sniff: 16 uniform halfwords from one cache line ----
__device__ __forceinline__ int sniff_isbf(const void* p)
{
    const unsigned short* x = (const unsigned short*)p;
    int cnt = 0;
    #pragma unroll
    for (int i = 0; i < 16; ++i) {
        int e = (x[2 * i] >> 7) & 0xFF;
        cnt += (e >= 90 && e <= 143) ? 1 : 0;
    }
    return cnt > 8;
}

// ================= fused preprocessing: one launch, 3 independent jobs =================
// blocks [0,1280): x transpose+cvt, VECTORIZED (f32x4 loads, bf16x4 stores)
// blocks [1280,1344): weight prep (own 65-stride view of the shared pool)
// blocks [1344,1664): bias table, packed bf16 (per-head blocks: keeps all blocks light,
//   since k_pre's 1664 blocks are fully co-resident -> duration = slowest block)
__global__ __launch_bounds__(256) void k_pre(
    const void* __restrict__ x, const void* __restrict__ Wqkv,
    const void* __restrict__ Wout, const void* __restrict__ rel,
    __bf16* __restrict__ xT, __bf16* __restrict__ Wt, __bf16* __restrict__ WoT,
    __bf16* __restrict__ biasC)
{
    __shared__ __align__(16) float shpool[64 * 68];   // 17.4 KB, shared by both tile users
    int bid = blockIdx.x;
    if (bid < 1280) {
        // ---- x transpose, vectorized ----
        float (*tile)[68] = (float(*)[68])shpool;     // stride 68: 16B-aligned rows
        int isbf = sniff_isbf(x);
        int b = bid / 40, rem = bid % 40;
        int c0 = (rem % 10) * 64, r0 = (rem / 10) * 64;
        const int R = 256, C = 625;
        int t = threadIdx.x;
        int lr4 = (t >> 4) * 4;    // 0..60
        int lc4 = (t & 15) * 4;    // 0..60
        const unsigned short* sb = (const unsigned short*)x + (size_t)b * (256 * 625);
        const float*          sf = (const float*)x          + (size_t)b * (256 * 625);
        #pragma unroll
        for (int rr = 0; rr < 4; ++rr) {
            int r = r0 + lr4 + rr;
            int c = c0 + lc4;
            f32x4 v = {0.f, 0.f, 0.f, 0.f};
            if (c + 3 < C) {
                if (isbf) {
                    u16x4 u = *(const u16x4*)(sb + (size_t)r * C + c);
                    #pragma unroll
                    for (int j = 0; j < 4; ++j) v[j] = __uint_as_float((unsigned)u[j] << 16);
                } else {
                    v = *(const f32x4u*)(sf + (size_t)r * C + c);
                }
            } else {
                #pragma unroll
                for (int j = 0; j < 4; ++j) {
                    int cc2 = c + j;
                    if (cc2 < C) {
                        if (isbf) v[j] = __uint_as_float((unsigned)sb[(size_t)r * C + cc2] << 16);
                        else      v[j] = sf[(size_t)r * C + cc2];
                    }
                }
            }
            *(f32x4*)(&tile[lr4 + rr][lc4]) = v;
        }
        __syncthreads();
        __bf16* d = xT + (size_t)b * (640 * 256);
        int lc = t & 63, rc = (t >> 6) * 16;
        int c = c0 + lc;
        #pragma unroll
        for (int k = 0; k < 4; ++k) {
            bf16x4 o4;
            #pragma unroll
            for (int j = 0; j < 4; ++j) o4[j] = (__bf16)tile[rc + k * 4 + j][lc];
            *(bf16x4*)(d + (size_t)c * R + r0 + rc + k * 4) = o4;
        }
    } else if (bid < 1344) {
        // ---- weight prep ----
        float (*tile)[65] = (float(*)[65])shpool;
        int q = bid - 1280;
        int bx = q % 16, by = q / 16;
        int isbf = sniff_isbf(Wqkv);
        int isqkv = (bx < 12);
        int bxx = isqkv ? bx : (bx - 12);
        const void* src = isqkv ? Wqkv : Wout;
        __bf16* dst = isqkv ? Wt : WoT;
        int R = 256, C = isqkv ? 768 : 256;
        int r0 = by * 64, c0 = bxx * 64;
        int tc = threadIdx.x & 63, tg = threadIdx.x >> 6;
        const unsigned short* sb = (const unsigned short*)src;
        const float*          sf = (const float*)src;
        #pragma unroll
        for (int rr = 0; rr < 16; ++rr) {
            int r = r0 + tg * 16 + rr, c = c0 + tc;
            float v;
            if (isbf) v = __uint_as_float((unsigned int)sb[r * C + c] << 16);
            else      v = sf[r * C + c];
            tile[tg * 16 + rr][tc] = v;
        }
        __syncthreads();
        const float qs = 0.25503494f;  // 32^-0.5 * log2(e)
        #pragma unroll
        for (int rr = 0; rr < 16; ++rr) {
            int c = c0 + tg * 16 + rr, r = r0 + tc;
            float v = tile[tc][tg * 16 + rr];
            if (isqkv && c < 256) v *= qs;
            dst[(size_t)c * R + r] = (__bf16)v;
        }
    } else {
        // ---- bias table (packed per-lane layout, bf16) ----
        const float LOG2E = 1.4426950408889634f;
        int isbf = sniff_isbf(rel);
        int q = bid - 1344;
        int ig = q % 40, h = q / 40;
        for (int t0 = 0; t0 < 10; ++t0) {
            int t  = t0 * 256 + threadIdx.x;
            int jc = t >> 7;
            int js = (t >> 6) & 1;
            int ln = t & 63;
            int qd = ln >> 4, l = ln & 15;
            int i = ig * 16 + l;
            int di = div25(i), ri = i - 25 * di;
            bf16x4 out;
            #pragma unroll
            for (int rr = 0; rr < 4; ++rr) {
                int j = jc * 32 + js * 16 + qd * 4 + rr;
                float v;
                if (j >= 625) {
                    v = -43281.f;
                } else {
                    int dj = div25(j);
                    int idx = (di - dj + 24) * 49 + ri - (j - 25 * dj) + 24;
                    idx = min(max(idx, 0), 2400);
                    float r;
                    if (isbf) r = (float)((const __bf16*)rel)[idx * 8 + h];
                    else      r = ((const float*)rel)[idx * 8 + h];
                    v = r * LOG2E;
                }
                out[rr] = (__bf16)v;
            }
            *(bf16x4*)(biasC + ((size_t)(h * 40 + ig) * 20 + jc) * 512 + ln * 8 + js * 4) = out;
        }
    }
}

// -------- QKV projection, 128x128 tile, BK=32, 2-phase double-buffered gll16 ----------
// (byte-identical to R7/R8/R9)
#define AS(bf, r, c) pool[(size_t)(bf) * 8192 + (size_t)(r) * 32 + (c)]
#define BS(bf, r, c) pool[(size_t)(bf) * 8192 + 4096 + (size_t)(r) * 32 + (c)]
#define CS(r, c)     pool[(size_t)(r) * 44 + (c)]
__global__ __launch_bounds__(256, 2) void k_qkv(
    const __bf16* __restrict__ xT,   // (b,640,256), pad rows zeroed
    const __bf16* __restrict__ Wt,   // (768,256)
    __bf16* __restrict__ Q,          // (b,8,640,32) scaled by 32^-.5*log2e
    __bf16* __restrict__ Km,         // (b,8,640,32)
    __bf16* __restrict__ Vt)         // (b,8,32,640)
{
    __shared__ __align__(16) __bf16 pool[16384];
    int L = blockIdx.x;
    int xcd = L & 7;
    int cc  = L >> 3;
    int pairIdx = xcd * 20 + cc / 6;
    int jt = cc - (cc / 6) * 6;
    int b  = pairIdx / 5;
    int pt = pairIdx - b * 5;
    int p0 = pt * 128, j0 = jt * 128;
    int tid = threadIdx.x;
    int w = tid >> 6, lane = tid & 63;
    int quad = lane >> 4, l15 = lane & 15;
    int wr = w >> 1, wc = w & 1;

    int srow = tid >> 2, scg = (tid & 3) * 8;
    const __bf16* ag  = xT + ((size_t)(b * 640 + p0 + srow) * 256) + scg;
    const __bf16* ag2 = ag + 64 * 256;
    const __bf16* bg  = Wt + ((size_t)(j0 + srow) * 256) + scg;
    const __bf16* bg2 = bg + 64 * 256;

    gll16(ag,  &AS(0, srow, scg));
    gll16(ag2, &AS(0, 64 + srow, scg));
    gll16(bg,  &BS(0, srow, scg));
    gll16(bg2, &BS(0, 64 + srow, scg));
    __syncthreads();

    f32x4 acc[4][4] = {};
    for (int kk = 0; kk < 8; ++kk) {
        int cur = kk & 1;
        if (kk < 7) {
            int c0 = (kk + 1) * 32;
            int nb = cur ^ 1;
            gll16(ag  + c0, &AS(nb, srow, scg));
            gll16(ag2 + c0, &AS(nb, 64 + srow, scg));
            gll16(bg  + c0, &BS(nb, srow, scg));
            gll16(bg2 + c0, &BS(nb, 64 + srow, scg));
        }
        bf16x8 af[4], bfr[4];
        #pragma unroll
        for (int t = 0; t < 4; ++t) {
            af[t]  = *(const bf16x8*)(&AS(cur, wr * 64 + t * 16 + l15, quad * 8));
            bfr[t] = *(const bf16x8*)(&BS(cur, wc * 64 + t * 16 + l15, quad * 8));
        }
        #pragma unroll
        for (int i = 0; i < 4; ++i)
            #pragma unroll
            for (int j = 0; j < 4; ++j)
                acc[i][j] = __builtin_amdgcn_mfma_f32_16x16x32_bf16(af[i], bfr[j], acc[i][j], 0, 0, 0);
        __syncthreads();
    }

    if (jt < 4) {
        for (int r = 0; r < 4; ++r) {
            __syncthreads();
            if (wc == (r >> 1)) {
                #pragma unroll
                for (int i = 0; i < 4; ++i) {
                    #pragma unroll
                    for (int js = 0; js < 2; ++js) {
                        int jp = (r & 1) * 2 + js;
                        int col = js * 16 + l15;
                        int prow = wr * 64 + i * 16 + quad * 4;
                        #pragma unroll
                        for (int rr = 0; rr < 4; ++rr)
                            CS(prow + rr, col) = (__bf16)acc[i][jp][rr];
                    }
                }
            }
            __syncthreads();
            int jj = j0 + r * 32;
            __bf16* dst; int hh;
            if (jj < 256) { hh = jj >> 5; dst = Q; }
            else          { hh = (jj - 256) >> 5; dst = Km; }
            int p = tid >> 1, d0 = (tid & 1) * 16;
            size_t base = ((size_t)((b * 8 + hh) * 640) + p0 + p) * 32 + d0;
            #pragma unroll
            for (int k4 = 0; k4 < 4; ++k4) {
                bf16x4 v4 = *(const bf16x4*)(&CS(p, d0 + k4 * 4));
                *(bf16x4*)(dst + base + k4 * 4) = v4;
            }
        }
    } else {
        #pragma unroll
        for (int i = 0; i < 4; ++i) {
            #pragma unroll
            for (int j = 0; j < 4; ++j) {
                int jj = j0 + wc * 64 + j * 16 + l15 - 512;
                int h = jj >> 5, t = jj & 31;
                int p = p0 + wr * 64 + i * 16 + quad * 4;
                bf16x4 vv;
                #pragma unroll
                for (int rr = 0; rr < 4; ++rr) vv[rr] = (__bf16)acc[i][j][rr];
                *(bf16x4*)(Vt + ((size_t)((b * 8 + h) * 32) + t) * 640 + p) = vv;
            }
        }
    }
}

// -------- fused attention v14: one 640-thread block per bh (byte-identical to R9) -----
__global__ __launch_bounds__(640, 2) void k_attn(
    const __bf16* __restrict__ Q,
    const __bf16* __restrict__ Km,
    const __bf16* __restrict__ Vt,
    const __bf16* __restrict__ biasC,  // packed C-fragment order, *log2e
    __bf16* __restrict__ ctx)          // (b,640,256), channel = h*32+dh
{
    __shared__ __align__(16) __bf16 P[10][2][64][44];  // [wave][buf][i][j] 112.5 KB
    __shared__ float ssum[10][64];
    int bh = blockIdx.x, b = bh >> 3, h = bh & 7;
    int tid = threadIdx.x, w = tid >> 6, lane = tid & 63;
    int quad = lane >> 4, l15 = lane & 15;
    int i0 = w * 64;

    bf16x8 qa[4];
    #pragma unroll
    for (int m = 0; m < 4; ++m)
        qa[m] = *(const bf16x8*)(Q + ((size_t)bh * 640 + i0 + 16 * m + l15) * 32 + quad * 8);
    const __bf16* kbase = Km + (size_t)bh * 640 * 32 + quad * 8;
    const __bf16* vbase = Vt + ((size_t)bh * 32 + l15) * 640 + quad * 8;
    const __bf16* bcb   = biasC + (size_t)(h * 40 + (i0 >> 4)) * 10240 + lane * 8;

    f32x4 o[4][2] = {};
    float psum[4] = {0.f, 0.f, 0.f, 0.f};

    bf16x8 k0 = *(const bf16x8*)(kbase + (size_t)l15 * 32);
    bf16x8 k1 = *(const bf16x8*)(kbase + (size_t)(16 + l15) * 32);
    bf16x8 bc[4];
    #pragma unroll
    for (int m = 0; m < 4; ++m)
        bc[m] = *(const bf16x8*)(bcb + m * 10240);
    bf16x8 vC0 = {}, vC1 = {};

    for (int c = 0; c < 20; ++c) {
        int buf = c & 1;
        f32x4 s[4][2];
        __builtin_amdgcn_s_setprio(1);
        #pragma unroll
        for (int m = 0; m < 4; ++m) {
            f32x4 f0, f1;
            #pragma unroll
            for (int rr = 0; rr < 4; ++rr) { f0[rr] = (float)bc[m][rr]; f1[rr] = (float)bc[m][4 + rr]; }
            s[m][0] = __builtin_amdgcn_mfma_f32_16x16x32_bf16(k0, qa[m], f0, 0, 0, 0);
            s[m][1] = __builtin_amdgcn_mfma_f32_16x16x32_bf16(k1, qa[m], f1, 0, 0, 0);
        }
        __builtin_amdgcn_s_setprio(0);
        int cn = min(c + 1, 19);
        bf16x8 k0n = *(const bf16x8*)(kbase + (size_t)(cn * 32 + l15) * 32);
        bf16x8 k1n = *(const bf16x8*)(kbase + (size_t)(cn * 32 + 16 + l15) * 32);
        bf16x8 vN0 = *(const bf16x8*)(vbase + c * 32);
        bf16x8 vN1 = *(const bf16x8*)(vbase + (size_t)16 * 640 + c * 32);
        bf16x8 bn[4];
        #pragma unroll
        for (int m = 0; m < 4; ++m)
            bn[m] = *(const bf16x8*)(bcb + m * 10240 + cn * 512);
        bf16x4 pk[4][2];
        #pragma unroll
        for (int m = 0; m < 4; ++m) {
            #pragma unroll
            for (int rr = 0; rr < 4; ++rr) {
                float e0 = fast_exp2(s[m][0][rr]); psum[m] += e0; pk[m][0][rr] = (__bf16)e0;
                float e1 = fast_exp2(s[m][1][rr]); psum[m] += e1; pk[m][1][rr] = (__bf16)e1;
            }
        }
        if (c > 0) {
            __builtin_amdgcn_s_setprio(1);
            #pragma unroll
            for (int m = 0; m < 4; ++m) {
                bf16x8 pa = *(const bf16x8*)(&P[w][buf ^ 1][16 * m + l15][quad * 8]);
                o[m][0] = __builtin_amdgcn_mfma_f32_16x16x32_bf16(pa, vC0, o[m][0], 0, 0, 0);
                o[m][1] = __builtin_amdgcn_mfma_f32_16x16x32_bf16(pa, vC1, o[m][1], 0, 0, 0);
            }
            __builtin_amdgcn_s_setprio(0);
        }
        #pragma unroll
        for (int m = 0; m < 4; ++m) {
            *(bf16x4*)(&P[w][buf][16 * m + l15][quad * 4])      = pk[m][0];
            *(bf16x4*)(&P[w][buf][16 * m + l15][16 + quad * 4]) = pk[m][1];
        }
        k0 = k0n; k1 = k1n; vC0 = vN0; vC1 = vN1;
        #pragma unroll
        for (int m = 0; m < 4; ++m) bc[m] = bn[m];
    }
    __builtin_amdgcn_s_setprio(1);
    #pragma unroll
    for (int m = 0; m < 4; ++m) {
        bf16x8 pa = *(const bf16x8*)(&P[w][1][16 * m + l15][quad * 8]);
        o[m][0] = __builtin_amdgcn_mfma_f32_16x16x32_bf16(pa, vC0, o[m][0], 0, 0, 0);
        o[m][1] = __builtin_amdgcn_mfma_f32_16x16x32_bf16(pa, vC1, o[m][1], 0, 0, 0);
    }
    __builtin_amdgcn_s_setprio(0);

    #pragma unroll
    for (int m = 0; m < 4; ++m) {
        psum[m] += __shfl_xor(psum[m], 16);
        psum[m] += __shfl_xor(psum[m], 32);
    }
    if (quad == 0)
        #pragma unroll
        for (int m = 0; m < 4; ++m) ssum[w][16 * m + l15] = psum[m];
    #pragma unroll
    for (int m = 0; m < 4; ++m) {
        #pragma unroll
        for (int rr = 0; rr < 4; ++rr) {
            int il = 16 * m + quad * 4 + rr;
            float inv = 1.f / ssum[w][il];
            size_t base = ((size_t)b * 640 + i0 + il) * 256 + h * 32;
            ctx[base + l15]      = (__bf16)(o[m][0][rr] * inv);
            ctx[base + 16 + l15] = (__bf16)(o[m][1][rr] * inv);
        }
    }
}

// -------- output projection, 2-phase gll16 pipeline + VECTORIZED stores ---------------
// (byte-identical to R8/R9 — the R10 LDS-transpose epilogue had an 8-way bank conflict)
__global__ __launch_bounds__(256, 2) void k_outproj(
    const __bf16* __restrict__ ctx,   // (b,640,256)
    const __bf16* __restrict__ WoT,   // (256,256)
    const void* __restrict__ xorig,   // dtype sniff only
    void* __restrict__ out)           // (b,256,625)
{
    __shared__ __align__(16) __bf16 pool2[20480];
    int isbf = sniff_isbf(xorig);
    int b = blockIdx.y, pt = blockIdx.x;
    int p0 = pt * 64;
    int tid = threadIdx.x, w = tid >> 6, lane = tid & 63;
    int quad = lane >> 4, l15 = lane & 15;
    int srow = tid >> 2, scg = (tid & 3) * 8;
    const __bf16* ag = ctx + ((size_t)(b * 640 + p0 + srow) * 256) + scg;
    const __bf16* bg = WoT + (size_t)srow * 256 + scg;

    gll16(ag,            &pool2[(size_t)srow * 32 + scg]);
    gll16(bg,            &pool2[2048 + (size_t)srow * 32 + scg]);
    gll16(bg + 64 * 256, &pool2[2048 + (size_t)(64 + srow) * 32 + scg]);
    gll16(bg + 128 * 256,&pool2[2048 + (size_t)(128 + srow) * 32 + scg]);
    gll16(bg + 192 * 256,&pool2[2048 + (size_t)(192 + srow) * 32 + scg]);
    __syncthreads();

    f32x4 acc[4][4] = {};
    for (int kk = 0; kk < 8; ++kk) {
        int cur = kk & 1;
        size_t base = (size_t)cur * 10240;
        if (kk < 7) {
            int c0 = (kk + 1) * 32;
            size_t nb = (size_t)(cur ^ 1) * 10240;
            gll16(ag + c0,             &pool2[nb + (size_t)srow * 32 + scg]);
            gll16(bg + c0,             &pool2[nb + 2048 + (size_t)srow * 32 + scg]);
            gll16(bg + 64 * 256 + c0,  &pool2[nb + 2048 + (size_t)(64 + srow) * 32 + scg]);
            gll16(bg + 128 * 256 + c0, &pool2[nb + 2048 + (size_t)(128 + srow) * 32 + scg]);
            gll16(bg + 192 * 256 + c0, &pool2[nb + 2048 + (size_t)(192 + srow) * 32 + scg]);
        }
        bf16x8 af[4], bfr[4];
        #pragma unroll
        for (int t = 0; t < 4; ++t) {
            af[t]  = *(const bf16x8*)(&pool2[base + (size_t)(t * 16 + l15) * 32 + quad * 8]);
            bfr[t] = *(const bf16x8*)(&pool2[base + 2048 + (size_t)(w * 64 + t * 16 + l15) * 32 + quad * 8]);
        }
        #pragma unroll
        for (int i = 0; i < 4; ++i)
            #pragma unroll
            for (int j = 0; j < 4; ++j)
                acc[i][j] = __builtin_amdgcn_mfma_f32_16x16x32_bf16(af[i], bfr[j], acc[i][j], 0, 0, 0);
        __syncthreads();
    }
    __bf16* outb = (__bf16*)out;
    float*  outf = (float*)out;
    #pragma unroll
    for (int i = 0; i < 4; ++i) {
        int p = p0 + i * 16 + quad * 4;
        #pragma unroll
        for (int j = 0; j < 4; ++j) {
            int co = w * 64 + j * 16 + l15;
            size_t o = ((size_t)(b * 256) + co) * 625 + p;
            if (p + 3 < 625) {
                if (isbf) {
                    bf16x4 v4;
                    #pragma unroll
                    for (int rr = 0; rr < 4; ++rr) v4[rr] = (__bf16)acc[i][j][rr];
                    *(bf16x4u*)(outb + o) = v4;
                } else {
                    *(f32x4u*)(outf + o) = acc[i][j];
                }
            } else {
                #pragma unroll
                for (int rr = 0; rr < 4; ++rr) {
                    if (p + rr < 625) {
                        if (isbf) outb[o + rr] = (__bf16)acc[i][j][rr];
                        else      outf[o + rr] = acc[i][j][rr];
                    }
                }
            }
        }
    }
}

extern "C" void kernel_launch(void* const* d_in, const int* in_sizes, int n_in,
                              void* d_out, int out_size, void* d_ws, size_t ws_size,
                              hipStream_t stream)
{
    const void* x    = d_in[0];
    const void* Wqkv = d_in[1];
    const void* Wout = d_in[2];
    const void* rel  = d_in[3];

    // ws layout, NO aliasing (ws_size is 256 MiB per the harness fill; we use ~70 MB).
    __bf16* ws    = (__bf16*)d_ws;
    __bf16* xT    = ws;                      // 10,485,760 elems
    __bf16* Wt    = xT + 10485760;           //    196,608
    __bf16* WoT   = Wt + 196608;             //     65,536
    __bf16* Q     = WoT + 65536;             //  5,242,880
    __bf16* Km    = Q + 5242880;             //  5,242,880
    __bf16* Vt    = Km + 5242880;            //  5,242,880
    __bf16* biasC = Vt + 5242880;            //  3,276,800
    __bf16* ctx   = biasC + 3276800;         //  5,242,880   (total ~70 MB)

    k_pre<<<1664, 256, 0, stream>>>(x, Wqkv, Wout, rel, xT, Wt, WoT, biasC);
    k_qkv<<<dim3(960), 256, 0, stream>>>(xT, Wt, Q, Km, Vt);
    k_attn<<<dim3(256), 640, 0, stream>>>(Q, Km, Vt, biasC, ctx);
    k_outproj<<<dim3(10, 32), 256, 0, stream>>>(ctx, WoT, x, d_out);
}